// Round 5
// baseline (174.579 us; speedup 1.0000x reference)
//
#include <hip/hip_runtime.h>

// SpatialBorderLoss — fused single-kernel, nt loads, 512-row tiles.
//
// R4 post-mortem: per-point, unrolled, and LDS variants ALL ~40-45us vs 17us
// traffic floor (2.6 TB/s read; harness fill does 6.6 TB/s write). Attacking
// remaining modeled terms: block churn (512-thread/512-row tiles halve block
// count, still 32 waves/CU @ 36.9KB LDS), L3 pollution from harness poison
// (non-temporal loads on all read-once streams), dispatch overhead (finalize
// fused via threadfence + atomic last-block-done; 4B memset for the counter).
//
// ws layout: [0]        uint done_counter   (memset 0 per launch)
//            [16]       double part_sum[nb]
//            [16+8nb]   uint   part_cnt[nb]
//            [16+12nb]  uint   part_wpos[nb]

typedef float v4f __attribute__((ext_vector_type(4)));

#define SBL_BLOCK 512
#define SBL_TILE  512

__global__ void __launch_bounds__(SBL_BLOCK) sbl_fused(
    const float* __restrict__ pts,      // [n,18]
    const float* __restrict__ quads,    // [n,8]
    const float* __restrict__ weight,   // [n]
    unsigned int* __restrict__ done,
    double* __restrict__ part_sum,
    unsigned int* __restrict__ part_cnt,
    unsigned int* __restrict__ part_wpos,
    float* __restrict__ out,
    int n, int nblocks)
{
    __shared__ float s_pts[SBL_TILE * 18];          // 36864 B
    __shared__ float        r_sum[8];
    __shared__ unsigned int r_cnt[8];
    __shared__ unsigned int r_wpos[8];
    __shared__ unsigned int s_isLast;
    __shared__ double       f_sum[8];
    __shared__ unsigned int f_cnt[8];
    __shared__ unsigned int f_wpos[8];

    const int tid  = threadIdx.x;
    const int base = blockIdx.x * SBL_TILE;
    int rows = n - base; if (rows > SBL_TILE) rows = SBL_TILE;
    const bool have_row = (tid < rows);

    // ---- early per-thread loads (quad + weight), non-temporal ----
    v4f qa = {0.f, 0.f, 0.f, 0.f};
    v4f qb = {0.f, 0.f, 0.f, 0.f};
    float wv = 0.0f;
    if (have_row) {
        const v4f* q4 = reinterpret_cast<const v4f*>(quads) + (size_t)(base + tid) * 2;
        qa = __builtin_nontemporal_load(q4);
        qb = __builtin_nontemporal_load(q4 + 1);
        wv = __builtin_nontemporal_load(&weight[base + tid]);
    }

    // ---- stage pts tile into LDS: coalesced nt float4 streaming ----
    {
        const v4f* g4 = reinterpret_cast<const v4f*>(pts + (size_t)base * 18);
        v4f* s4 = reinterpret_cast<v4f*>(s_pts);
        const int nfloats = rows * 18;
        const int nf4 = nfloats >> 2;               // rows even -> exact
        for (int idx = tid; idx < nf4; idx += SBL_BLOCK)
            s4[idx] = __builtin_nontemporal_load(&g4[idx]);
        for (int idx = (nf4 << 2) + tid; idx < nfloats; idx += SBL_BLOCK)
            s_pts[idx] = pts[(size_t)base * 18 + idx];
    }
    __syncthreads();

    float local_sum = 0.0f;
    unsigned int local_cnt = 0u;
    unsigned int local_wpos = (wv > 0.0f) ? 1u : 0u;

    // ---- compute: thread t = row t, 9 points from LDS ----
    if (have_row) {
        const float vx0 = qa.x, vy0 = qa.y, vx1 = qa.z, vy1 = qa.w;
        const float vx2 = qb.x, vy2 = qb.y, vx3 = qb.z, vy3 = qb.w;
        const float cx = (vx0 + vx2) * 0.5f;
        const float cy = (vy0 + vy2) * 0.5f;
        // edge e pairs (v_e, v_{e-1 mod 4}) per jnp.roll(v,1)
        const float d0 = vy3 - vy0, d1 = vy0 - vy1, d2 = vy1 - vy2, d3 = vy2 - vy3;
        const float e0 = vx3 - vx0, e1 = vx0 - vx1, e2 = vx1 - vx2, e3 = vx2 - vx3;
        const bool  n0 = d0 < 0.0f, n1 = d1 < 0.0f, n2 = d2 < 0.0f, n3 = d3 < 0.0f;

        const float2* prow = reinterpret_cast<const float2*>(s_pts + tid * 18);
        #pragma unroll
        for (int k = 0; k < 9; ++k) {
            const float2 p = prow[k];
            const float px = p.x, py = p.y;

            const bool c0 = vy0 > py, c1 = vy1 > py, c2 = vy2 > py, c3 = vy3 > py;
            const bool s0 = c0 != c3, s1 = c1 != c0, s2 = c2 != c1, s3 = c3 != c2;

            // straddle pins sign of d; divide -> sign-adjusted mul-compare
            const float t0 = py - vy0, t1 = py - vy1, t2 = py - vy2, t3 = py - vy3;
            const float m0 = e0 * t0, m1 = e1 * t1, m2 = e2 * t2, m3 = e3 * t3;
            const float l0 = (px - vx0) * d0, l1 = (px - vx1) * d1;
            const float l2 = (px - vx2) * d2, l3 = (px - vx3) * d3;

            const bool x0 = s0 && ((l0 < m0) != n0);
            const bool x1 = s1 && ((l1 < m1) != n1);
            const bool x2 = s2 && ((l2 < m2) != n2);
            const bool x3 = s3 && ((l3 < m3) != n3);

            const bool inside = (x0 != x1) != (x2 != x3);   // parity
            if (!inside) {
                const float dx = px - cx;
                const float dy = py - cy;
                local_sum += sqrtf(fmaf(dx, dx, dy * dy));  // 0.2 folded into epilogue
                local_cnt += 1u;
            }
        }
    }

    // ---- wave (64) reduction ----
    #pragma unroll
    for (int off = 32; off > 0; off >>= 1) {
        local_sum  += __shfl_down(local_sum, off, 64);
        local_cnt  += __shfl_down(local_cnt, off, 64);
        local_wpos += __shfl_down(local_wpos, off, 64);
    }

    // ---- block reduction across 8 waves ----
    const int lane = tid & 63;
    const int wave = tid >> 6;
    if (lane == 0) { r_sum[wave] = local_sum; r_cnt[wave] = local_cnt; r_wpos[wave] = local_wpos; }
    __syncthreads();
    if (tid == 0) {
        double bsum = 0.0;
        unsigned int bcnt = 0u, bwpos = 0u;
        #pragma unroll
        for (int i = 0; i < 8; ++i) { bsum += (double)r_sum[i]; bcnt += r_cnt[i]; bwpos += r_wpos[i]; }
        part_sum[blockIdx.x]  = bsum;
        part_cnt[blockIdx.x]  = bcnt;
        part_wpos[blockIdx.x] = bwpos;
        __threadfence();                              // release partials (device scope)
        unsigned int prev = atomicAdd(done, 1u);      // device-scope atomic
        s_isLast = (prev == (unsigned int)(nblocks - 1)) ? 1u : 0u;
    }
    __syncthreads();

    // ---- last block finalizes (fused epilogue) ----
    if (s_isLast) {
        __threadfence();                              // acquire
        double s = 0.0;
        unsigned int c = 0u, w = 0u;
        for (int i = tid; i < nblocks; i += SBL_BLOCK) {
            s += part_sum[i];
            c += part_cnt[i];
            w += part_wpos[i];
        }
        #pragma unroll
        for (int off = 32; off > 0; off >>= 1) {
            s += __shfl_down(s, off, 64);
            c += __shfl_down(c, off, 64);
            w += __shfl_down(w, off, 64);
        }
        if (lane == 0) { f_sum[wave] = s; f_cnt[wave] = c; f_wpos[wave] = w; }
        __syncthreads();
        if (tid == 0) {
            double ts = 0.0; unsigned int tc = 0u, tw = 0u;
            #pragma unroll
            for (int i = 0; i < 8; ++i) { ts += f_sum[i]; tc += f_cnt[i]; tw += f_wpos[i]; }
            const double loss_sb = (tc > 0u) ? (0.2 * ts / (double)tc) : 0.0;
            const double avg_factor = (double)tw + 1e-6;
            out[0] = (float)(loss_sb / avg_factor);
        }
    }
}

extern "C" void kernel_launch(void* const* d_in, const int* in_sizes, int n_in,
                              void* d_out, int out_size, void* d_ws, size_t ws_size,
                              hipStream_t stream) {
    const float* pts    = (const float*)d_in[0];   // [n,18]
    const float* quads  = (const float*)d_in[1];   // [n,8]
    const float* weight = (const float*)d_in[2];   // [n]
    float* out = (float*)d_out;

    const int n = in_sizes[2];
    const int nblocks = (n + SBL_TILE - 1) / SBL_TILE;

    unsigned int* done      = (unsigned int*)d_ws;
    double*       part_sum  = (double*)((char*)d_ws + 16);
    unsigned int* part_cnt  = (unsigned int*)((char*)d_ws + 16 + (size_t)nblocks * 8);
    unsigned int* part_wpos = (unsigned int*)((char*)d_ws + 16 + (size_t)nblocks * 12);

    hipMemsetAsync(done, 0, sizeof(unsigned int), stream);   // ws is poisoned 0xAA pre-launch
    sbl_fused<<<nblocks, SBL_BLOCK, 0, stream>>>(pts, quads, weight,
                                                 done, part_sum, part_cnt, part_wpos,
                                                 out, n, nblocks);
}

// Round 6
// 134.267 us; speedup vs baseline: 1.3002x; 1.3002x over previous
//
#include <hip/hip_runtime.h>
#include <cstdint>

// SpatialBorderLoss — R4 structure + async global->LDS staging.
//
// R5 post-mortem: nt loads + per-block __threadfence + serial staging loop
// regressed main 30 -> 66us. All reverted. This round: R4 shape (256thr/256row,
// separate finalize, plain loads) with __builtin_amdgcn_global_load_lds(16B)
// staging: no VGPR round-trip, back-to-back chunk issues per wave, drained by
// the vmcnt(0) the compiler emits at __syncthreads. Wave w copies 1KB chunks
// w, w+4, ... (18 chunks); lane addr = base + lane*16 matches the
// wave-uniform-base + lane*size HW placement.
//
// ws: double part_sum[nb] ; uint part_cnt[nb] ; uint part_wpos[nb]

#define SBL_BLOCK 256
#define SBL_TILE  256

__global__ void __launch_bounds__(SBL_BLOCK) sbl_main(
    const float* __restrict__ pts,      // [n,18]
    const float* __restrict__ quads,    // [n,8]
    const float* __restrict__ weight,   // [n]
    double* __restrict__ part_sum,
    unsigned int* __restrict__ part_cnt,
    unsigned int* __restrict__ part_wpos,
    int n)
{
    __shared__ __align__(16) float s_pts[SBL_TILE * 18];   // 18432 B = 18 x 1KB chunks

    const int tid  = threadIdx.x;
    const int lane = tid & 63;
    const int wave = tid >> 6;
    const int base = blockIdx.x * SBL_TILE;
    int rows = n - base; if (rows > SBL_TILE) rows = SBL_TILE;
    const bool have_row = (tid < rows);

    // ---- per-thread quad + weight loads first (latency overlaps staging) ----
    float4 qa = make_float4(0.f, 0.f, 0.f, 0.f);
    float4 qb = make_float4(0.f, 0.f, 0.f, 0.f);
    float wv = 0.0f;
    if (have_row) {
        const float4* q4 = reinterpret_cast<const float4*>(quads) + (size_t)(base + tid) * 2;
        qa = q4[0];
        qb = q4[1];
        wv = weight[base + tid];
    }

    // ---- stage pts tile: async global->LDS, 16B/lane, 1KB chunk per wave-issue ----
    if (rows == SBL_TILE) {
        const char* gbase = (const char*)(pts + (size_t)base * 18);   // 16B aligned
        const uint32_t lds0 = (uint32_t)(uintptr_t)(void*)s_pts;      // low 32 bits = LDS offset
        #pragma unroll
        for (int c = 0; c < 5; ++c) {
            const int chunk = wave + 4 * c;            // wave-uniform
            if (chunk < 18) {
                const char* g = gbase + chunk * 1024 + lane * 16;
                __builtin_amdgcn_global_load_lds(
                    (const __attribute__((address_space(1))) void*)(uintptr_t)g,
                    (__attribute__((address_space(3))) void*)(uintptr_t)(lds0 + chunk * 1024 + lane * 16),
                    16, 0, 0);
            }
        }
    } else {                                           // tail tile (once per grid)
        const float2* g2 = reinterpret_cast<const float2*>(pts + (size_t)base * 18);
        float2* s2 = reinterpret_cast<float2*>(s_pts);
        const int nf2 = rows * 9;
        for (int idx = tid; idx < nf2; idx += SBL_BLOCK) s2[idx] = g2[idx];
    }
    __syncthreads();                                   // drains vmcnt (covers global_load_lds)

    float local_sum = 0.0f;
    unsigned int local_cnt = 0u;
    unsigned int local_wpos = (wv > 0.0f) ? 1u : 0u;

    // ---- compute: thread t = row t, 9 points from LDS ----
    if (have_row) {
        const float vx0 = qa.x, vy0 = qa.y, vx1 = qa.z, vy1 = qa.w;
        const float vx2 = qb.x, vy2 = qb.y, vx3 = qb.z, vy3 = qb.w;
        const float cx = (vx0 + vx2) * 0.5f;
        const float cy = (vy0 + vy2) * 0.5f;
        // edge e pairs (v_e, v_{e-1 mod 4}) per jnp.roll(v,1)
        const float d0 = vy3 - vy0, d1 = vy0 - vy1, d2 = vy1 - vy2, d3 = vy2 - vy3;
        const float e0 = vx3 - vx0, e1 = vx0 - vx1, e2 = vx1 - vx2, e3 = vx2 - vx3;
        const bool  n0 = d0 < 0.0f, n1 = d1 < 0.0f, n2 = d2 < 0.0f, n3 = d3 < 0.0f;

        const float2* prow = reinterpret_cast<const float2*>(s_pts + tid * 18);
        #pragma unroll
        for (int k = 0; k < 9; ++k) {
            const float2 p = prow[k];
            const float px = p.x, py = p.y;

            const bool c0 = vy0 > py, c1 = vy1 > py, c2 = vy2 > py, c3 = vy3 > py;
            const bool s0 = c0 != c3, s1 = c1 != c0, s2 = c2 != c1, s3 = c3 != c2;

            // straddle pins sign of d; divide -> sign-adjusted mul-compare
            const float t0 = py - vy0, t1 = py - vy1, t2 = py - vy2, t3 = py - vy3;
            const float m0 = e0 * t0, m1 = e1 * t1, m2 = e2 * t2, m3 = e3 * t3;
            const float l0 = (px - vx0) * d0, l1 = (px - vx1) * d1;
            const float l2 = (px - vx2) * d2, l3 = (px - vx3) * d3;

            const bool x0 = s0 && ((l0 < m0) != n0);
            const bool x1 = s1 && ((l1 < m1) != n1);
            const bool x2 = s2 && ((l2 < m2) != n2);
            const bool x3 = s3 && ((l3 < m3) != n3);

            const bool inside = (x0 != x1) != (x2 != x3);   // parity of crossings
            if (!inside) {
                const float dx = px - cx;
                const float dy = py - cy;
                local_sum += sqrtf(fmaf(dx, dx, dy * dy));  // 0.2 applied in finalize
                local_cnt += 1u;
            }
        }
    }

    // ---- wave (64) reduction ----
    #pragma unroll
    for (int off = 32; off > 0; off >>= 1) {
        local_sum  += __shfl_down(local_sum, off, 64);
        local_cnt  += __shfl_down(local_cnt, off, 64);
        local_wpos += __shfl_down(local_wpos, off, 64);
    }

    // ---- block reduction across 4 waves ----
    __shared__ float        r_sum[4];
    __shared__ unsigned int r_cnt[4];
    __shared__ unsigned int r_wpos[4];
    if (lane == 0) { r_sum[wave] = local_sum; r_cnt[wave] = local_cnt; r_wpos[wave] = local_wpos; }
    __syncthreads();
    if (tid == 0) {
        double bsum = 0.0;
        unsigned int bcnt = 0u, bwpos = 0u;
        #pragma unroll
        for (int i = 0; i < 4; ++i) { bsum += (double)r_sum[i]; bcnt += r_cnt[i]; bwpos += r_wpos[i]; }
        part_sum[blockIdx.x]  = bsum;      // own slot: no init, no atomics
        part_cnt[blockIdx.x]  = bcnt;
        part_wpos[blockIdx.x] = bwpos;
    }
}

__global__ void __launch_bounds__(1024) sbl_finalize(
    const double* __restrict__ part_sum,
    const unsigned int* __restrict__ part_cnt,
    const unsigned int* __restrict__ part_wpos,
    float* __restrict__ out,
    int nblocks)
{
    const int tid = threadIdx.x;           // 1024 threads = 16 waves
    double s = 0.0;
    unsigned int c = 0u, w = 0u;
    for (int i = tid; i < nblocks; i += 1024) {   // 4 independent iterations
        s += part_sum[i];
        c += part_cnt[i];
        w += part_wpos[i];
    }
    #pragma unroll
    for (int off = 32; off > 0; off >>= 1) {
        s += __shfl_down(s, off, 64);
        c += __shfl_down(c, off, 64);
        w += __shfl_down(w, off, 64);
    }
    __shared__ double       fs[16];
    __shared__ unsigned int fc[16], fw[16];
    const int lane = tid & 63, wave = tid >> 6;
    if (lane == 0) { fs[wave] = s; fc[wave] = c; fw[wave] = w; }
    __syncthreads();
    if (tid == 0) {
        double ts = 0.0; unsigned int tc = 0u, tw = 0u;
        #pragma unroll
        for (int k = 0; k < 16; ++k) { ts += fs[k]; tc += fc[k]; tw += fw[k]; }
        const double loss_sb = (tc > 0u) ? (0.2 * ts / (double)tc) : 0.0;
        const double avg_factor = (double)tw + 1e-6;
        out[0] = (float)(loss_sb / avg_factor);
    }
}

extern "C" void kernel_launch(void* const* d_in, const int* in_sizes, int n_in,
                              void* d_out, int out_size, void* d_ws, size_t ws_size,
                              hipStream_t stream) {
    const float* pts    = (const float*)d_in[0];   // [n,18]
    const float* quads  = (const float*)d_in[1];   // [n,8]
    const float* weight = (const float*)d_in[2];   // [n]
    float* out = (float*)d_out;

    const int n = in_sizes[2];
    const int nblocks = (n + SBL_TILE - 1) / SBL_TILE;

    double*       part_sum  = (double*)d_ws;
    unsigned int* part_cnt  = (unsigned int*)((char*)d_ws + (size_t)nblocks * sizeof(double));
    unsigned int* part_wpos = (unsigned int*)((char*)d_ws + (size_t)nblocks * (sizeof(double) + sizeof(unsigned int)));

    sbl_main<<<nblocks, SBL_BLOCK, 0, stream>>>(pts, quads, weight,
                                                part_sum, part_cnt, part_wpos, n);
    sbl_finalize<<<1, 1024, 0, stream>>>(part_sum, part_cnt, part_wpos, out, nblocks);
}

// Round 7
// 133.830 us; speedup vs baseline: 1.3045x; 1.0033x over previous
//
#include <hip/hip_runtime.h>
#include <cstdint>

// SpatialBorderLoss — R6 structure scaled to 512-row tiles.
//
// R6 post-mortem: global_load_lds(16B) staging WIN (140.8 -> 134.3 total,
// main ~25us vs 17us traffic floor). This round isolates tile size: 512
// rows/512 threads halves block count (3907 -> 1954) and per-block fixed
// costs. LDS 36.9KB -> 4 blocks/CU = 32 waves/CU (full). R5's 512-tile
// regression was confounded with nt loads + threadfence + serial staging —
// none of those here; byte-identical compute path to R6.
//
// ws: double part_sum[nb] ; uint part_cnt[nb] ; uint part_wpos[nb]

#define SBL_BLOCK 512
#define SBL_TILE  512
#define SBL_WAVES (SBL_BLOCK / 64)
#define SBL_CHUNKS (SBL_TILE * 72 / 1024)   // 36 x 1KB chunks

__global__ void __launch_bounds__(SBL_BLOCK) sbl_main(
    const float* __restrict__ pts,      // [n,18]
    const float* __restrict__ quads,    // [n,8]
    const float* __restrict__ weight,   // [n]
    double* __restrict__ part_sum,
    unsigned int* __restrict__ part_cnt,
    unsigned int* __restrict__ part_wpos,
    int n)
{
    __shared__ __align__(16) float s_pts[SBL_TILE * 18];   // 36864 B = 36 x 1KB chunks

    const int tid  = threadIdx.x;
    const int lane = tid & 63;
    const int wave = tid >> 6;
    const int base = blockIdx.x * SBL_TILE;
    int rows = n - base; if (rows > SBL_TILE) rows = SBL_TILE;
    const bool have_row = (tid < rows);

    // ---- stage pts tile first: async global->LDS, 16B/lane, 1KB chunk/issue ----
    if (rows == SBL_TILE) {
        const char* gbase = (const char*)(pts + (size_t)base * 18);   // 16B aligned
        const uint32_t lds0 = (uint32_t)(uintptr_t)(void*)s_pts;      // low 32 bits = LDS offset
        #pragma unroll
        for (int c = 0; c < (SBL_CHUNKS + SBL_WAVES - 1) / SBL_WAVES; ++c) {
            const int chunk = wave + SBL_WAVES * c;     // wave-uniform
            if (chunk < SBL_CHUNKS) {
                const char* g = gbase + chunk * 1024 + lane * 16;
                __builtin_amdgcn_global_load_lds(
                    (const __attribute__((address_space(1))) void*)(uintptr_t)g,
                    (__attribute__((address_space(3))) void*)(uintptr_t)(lds0 + chunk * 1024 + lane * 16),
                    16, 0, 0);
            }
        }
    } else {                                            // tail tile (once per grid)
        const float2* g2 = reinterpret_cast<const float2*>(pts + (size_t)base * 18);
        float2* s2 = reinterpret_cast<float2*>(s_pts);
        const int nf2 = rows * 9;
        for (int idx = tid; idx < nf2; idx += SBL_BLOCK) s2[idx] = g2[idx];
    }

    // ---- per-thread quad + weight loads (latency overlaps the LDS DMA) ----
    float4 qa = make_float4(0.f, 0.f, 0.f, 0.f);
    float4 qb = make_float4(0.f, 0.f, 0.f, 0.f);
    float wv = 0.0f;
    if (have_row) {
        const float4* q4 = reinterpret_cast<const float4*>(quads) + (size_t)(base + tid) * 2;
        qa = q4[0];
        qb = q4[1];
        wv = weight[base + tid];
    }
    __syncthreads();                                    // drains vmcnt (covers global_load_lds)

    float local_sum = 0.0f;
    unsigned int local_cnt = 0u;
    unsigned int local_wpos = (wv > 0.0f) ? 1u : 0u;

    // ---- compute: thread t = row t, 9 points from LDS ----
    if (have_row) {
        const float vx0 = qa.x, vy0 = qa.y, vx1 = qa.z, vy1 = qa.w;
        const float vx2 = qb.x, vy2 = qb.y, vx3 = qb.z, vy3 = qb.w;
        const float cx = (vx0 + vx2) * 0.5f;
        const float cy = (vy0 + vy2) * 0.5f;
        // edge e pairs (v_e, v_{e-1 mod 4}) per jnp.roll(v,1)
        const float d0 = vy3 - vy0, d1 = vy0 - vy1, d2 = vy1 - vy2, d3 = vy2 - vy3;
        const float e0 = vx3 - vx0, e1 = vx0 - vx1, e2 = vx1 - vx2, e3 = vx2 - vx3;
        const bool  n0 = d0 < 0.0f, n1 = d1 < 0.0f, n2 = d2 < 0.0f, n3 = d3 < 0.0f;

        const float2* prow = reinterpret_cast<const float2*>(s_pts + tid * 18);
        #pragma unroll
        for (int k = 0; k < 9; ++k) {
            const float2 p = prow[k];
            const float px = p.x, py = p.y;

            const bool c0 = vy0 > py, c1 = vy1 > py, c2 = vy2 > py, c3 = vy3 > py;
            const bool s0 = c0 != c3, s1 = c1 != c0, s2 = c2 != c1, s3 = c3 != c2;

            // straddle pins sign of d; divide -> sign-adjusted mul-compare
            const float t0 = py - vy0, t1 = py - vy1, t2 = py - vy2, t3 = py - vy3;
            const float m0 = e0 * t0, m1 = e1 * t1, m2 = e2 * t2, m3 = e3 * t3;
            const float l0 = (px - vx0) * d0, l1 = (px - vx1) * d1;
            const float l2 = (px - vx2) * d2, l3 = (px - vx3) * d3;

            const bool x0 = s0 && ((l0 < m0) != n0);
            const bool x1 = s1 && ((l1 < m1) != n1);
            const bool x2 = s2 && ((l2 < m2) != n2);
            const bool x3 = s3 && ((l3 < m3) != n3);

            const bool inside = (x0 != x1) != (x2 != x3);   // parity of crossings
            if (!inside) {
                const float dx = px - cx;
                const float dy = py - cy;
                local_sum += sqrtf(fmaf(dx, dx, dy * dy));  // 0.2 applied in finalize
                local_cnt += 1u;
            }
        }
    }

    // ---- wave (64) reduction ----
    #pragma unroll
    for (int off = 32; off > 0; off >>= 1) {
        local_sum  += __shfl_down(local_sum, off, 64);
        local_cnt  += __shfl_down(local_cnt, off, 64);
        local_wpos += __shfl_down(local_wpos, off, 64);
    }

    // ---- block reduction across waves ----
    __shared__ float        r_sum[SBL_WAVES];
    __shared__ unsigned int r_cnt[SBL_WAVES];
    __shared__ unsigned int r_wpos[SBL_WAVES];
    if (lane == 0) { r_sum[wave] = local_sum; r_cnt[wave] = local_cnt; r_wpos[wave] = local_wpos; }
    __syncthreads();
    if (tid == 0) {
        double bsum = 0.0;
        unsigned int bcnt = 0u, bwpos = 0u;
        #pragma unroll
        for (int i = 0; i < SBL_WAVES; ++i) { bsum += (double)r_sum[i]; bcnt += r_cnt[i]; bwpos += r_wpos[i]; }
        part_sum[blockIdx.x]  = bsum;      // own slot: no init, no atomics
        part_cnt[blockIdx.x]  = bcnt;
        part_wpos[blockIdx.x] = bwpos;
    }
}

__global__ void __launch_bounds__(1024) sbl_finalize(
    const double* __restrict__ part_sum,
    const unsigned int* __restrict__ part_cnt,
    const unsigned int* __restrict__ part_wpos,
    float* __restrict__ out,
    int nblocks)
{
    const int tid = threadIdx.x;           // 1024 threads = 16 waves
    double s = 0.0;
    unsigned int c = 0u, w = 0u;
    for (int i = tid; i < nblocks; i += 1024) {   // 2 independent iterations
        s += part_sum[i];
        c += part_cnt[i];
        w += part_wpos[i];
    }
    #pragma unroll
    for (int off = 32; off > 0; off >>= 1) {
        s += __shfl_down(s, off, 64);
        c += __shfl_down(c, off, 64);
        w += __shfl_down(w, off, 64);
    }
    __shared__ double       fs[16];
    __shared__ unsigned int fc[16], fw[16];
    const int lane = tid & 63, wave = tid >> 6;
    if (lane == 0) { fs[wave] = s; fc[wave] = c; fw[wave] = w; }
    __syncthreads();
    if (tid == 0) {
        double ts = 0.0; unsigned int tc = 0u, tw = 0u;
        #pragma unroll
        for (int k = 0; k < 16; ++k) { ts += fs[k]; tc += fc[k]; tw += fw[k]; }
        const double loss_sb = (tc > 0u) ? (0.2 * ts / (double)tc) : 0.0;
        const double avg_factor = (double)tw + 1e-6;
        out[0] = (float)(loss_sb / avg_factor);
    }
}

extern "C" void kernel_launch(void* const* d_in, const int* in_sizes, int n_in,
                              void* d_out, int out_size, void* d_ws, size_t ws_size,
                              hipStream_t stream) {
    const float* pts    = (const float*)d_in[0];   // [n,18]
    const float* quads  = (const float*)d_in[1];   // [n,8]
    const float* weight = (const float*)d_in[2];   // [n]
    float* out = (float*)d_out;

    const int n = in_sizes[2];
    const int nblocks = (n + SBL_TILE - 1) / SBL_TILE;

    double*       part_sum  = (double*)d_ws;
    unsigned int* part_cnt  = (unsigned int*)((char*)d_ws + (size_t)nblocks * sizeof(double));
    unsigned int* part_wpos = (unsigned int*)((char*)d_ws + (size_t)nblocks * (sizeof(double) + sizeof(unsigned int)));

    sbl_main<<<nblocks, SBL_BLOCK, 0, stream>>>(pts, quads, weight,
                                                part_sum, part_cnt, part_wpos, n);
    sbl_finalize<<<1, 1024, 0, stream>>>(part_sum, part_cnt, part_wpos, out, nblocks);
}